// Round 2
// baseline (308.401 us; speedup 1.0000x reference)
//
#include <hip/hip_runtime.h>
#include <math.h>

#define B_ 2
#define T_ 2048
#define C_ 1024
#define H_ 16
#define HD_ 64
#define M_ (B_*T_)

typedef _Float16 half2v __attribute__((ext_vector_type(2)));
typedef _Float16 half4v __attribute__((ext_vector_type(4)));
typedef _Float16 half8v __attribute__((ext_vector_type(8)));
typedef float f32x4 __attribute__((ext_vector_type(4)));

#define GLD_LDS(gp, lp) \
  __builtin_amdgcn_global_load_lds( \
      (const __attribute__((address_space(1))) void*)(gp), \
      (__attribute__((address_space(3))) void*)(lp), 16, 0, 0)

// ---------------------------------------------------------------------------
// Fused prep: fp32->f16 cast of x (blocks 0..4095), 4 weight transposes
// (blocks 4096..8191), bias concat (blocks 8192..8203). One launch.
// ---------------------------------------------------------------------------
__global__ __launch_bounds__(256) void prep_kernel(
    const float* __restrict__ x,
    const float* __restrict__ Wq, const float* __restrict__ Wk,
    const float* __restrict__ Wv, const float* __restrict__ Wo,
    const float* __restrict__ bq, const float* __restrict__ bk,
    const float* __restrict__ bv,
    _Float16* __restrict__ xh, _Float16* __restrict__ Wt3,
    _Float16* __restrict__ Wot, float* __restrict__ b3)
{
  __shared__ float tile[32][33];
  const int blk = blockIdx.x, thr = threadIdx.x;
  if (blk < 4096) {
    int i = blk * 256 + thr;
    float4 v = ((const float4*)x)[i];
    half4v h; h[0] = (_Float16)v.x; h[1] = (_Float16)v.y;
    h[2] = (_Float16)v.z; h[3] = (_Float16)v.w;
    ((half4v*)xh)[i] = h;
  } else if (blk < 8192) {
    int zz = (blk - 4096) >> 10;      // which W
    int bxy = (blk - 4096) & 1023;
    const float* W; _Float16* Wt;
    switch (zz) {
      case 0:  W = Wq; Wt = Wt3; break;
      case 1:  W = Wk; Wt = Wt3 + (size_t)1024 * 1024; break;
      case 2:  W = Wv; Wt = Wt3 + (size_t)2048 * 1024; break;
      default: W = Wo; Wt = Wot; break;
    }
    const int n0 = (bxy & 31) * 32, k0 = (bxy >> 5) * 32;
    const int tx = thr & 31, ty = thr >> 5;  // 32 x 8
#pragma unroll
    for (int r = 0; r < 4; r++) {
      int k = ty + r * 8;
      tile[k][tx] = W[(size_t)(k0 + k) * C_ + n0 + tx];
    }
    __syncthreads();
#pragma unroll
    for (int r = 0; r < 4; r++) {
      int n = ty + r * 8;
      Wt[(size_t)(n0 + n) * C_ + k0 + tx] = (_Float16)tile[tx][n];
    }
  } else {
    int i = (blk - 8192) * 256 + thr;  // 0..3071
    const float* s = (i < 1024) ? bq : ((i < 2048) ? bk : bv);
    b3[i] = s[i & 1023];
  }
}

// ---------------------------------------------------------------------------
// f16 MFMA GEMM: Out[M,N] = A[M,1024] @ Wt[N,1024]^T + bias.
// BK=32, 256 threads = 4 waves (2x2); wave tile (BM/2)x(BN/2).
// Staging via global_load_lds width=16 (m97 pattern).
// EPI 0: fused QKV epilogue. Q (scaled 0.125*log2e) and K: plain 2-B stores
//   (4 rows x 32-B runs per wave-store). V: r=0..3 are 4 CONSECUTIVE t in
//   Vt[b,h,d,t] -> packed into ONE 8-B store (4x fewer instrs, 4x better
//   line locality than the r9 2-B scatter).
// EPI 1: fp32 out + bias (of).
// ---------------------------------------------------------------------------
template <int BM, int BN, int EPI>
__global__ __launch_bounds__(256) void gemm_f16_kernel(
    const _Float16* __restrict__ A, const _Float16* __restrict__ Bw,
    const float* __restrict__ bias,
    _Float16* __restrict__ o0, _Float16* __restrict__ o1,
    _Float16* __restrict__ o2, float* __restrict__ of)
{
  constexpr int FM = BM / 32, FN = BN / 32;
  __shared__ __align__(16) _Float16 As[BM * 32];
  __shared__ __align__(16) _Float16 Bs[BN * 32];
  const int t = threadIdx.x;
  const int w = t >> 6, lane = t & 63, l15 = lane & 15, quad = lane >> 4;
  const int wm = (w & 1) * (BM / 2), wn = (w >> 1) * (BN / 2);
  const int bm = blockIdx.y * BM, bn = blockIdx.x * BN;
  const int lrow = lane >> 2, lcol = (lane & 3) * 8;  // staging: 16 rows/call

  f32x4 acc[FM][FN];
#pragma unroll
  for (int i = 0; i < FM; i++)
#pragma unroll
    for (int j = 0; j < FN; j++) acc[i][j] = (f32x4){0.f, 0.f, 0.f, 0.f};

  for (int k0 = 0; k0 < 1024; k0 += 32) {
#pragma unroll
    for (int i = 0; i < BM / 64; i++) {
      int ca = w + 4 * i;
      int row = ca * 16 + lrow;
      GLD_LDS(A + (size_t)(bm + row) * 1024 + k0 + lcol, As + ca * 512);
    }
#pragma unroll
    for (int i = 0; i < BN / 64; i++) {
      int cb = w + 4 * i;
      int row = cb * 16 + lrow;
      GLD_LDS(Bw + (size_t)(bn + row) * 1024 + k0 + lcol, Bs + cb * 512);
    }
    __syncthreads();

    half8v af[FM], bf[FN];
#pragma unroll
    for (int mt = 0; mt < FM; mt++)
      af[mt] = *(const half8v*)(As + (wm + mt * 16 + l15) * 32 + quad * 8);
#pragma unroll
    for (int nt = 0; nt < FN; nt++)
      bf[nt] = *(const half8v*)(Bs + (wn + nt * 16 + l15) * 32 + quad * 8);
#pragma unroll
    for (int mt = 0; mt < FM; mt++)
#pragma unroll
      for (int nt = 0; nt < FN; nt++)
        acc[mt][nt] = __builtin_amdgcn_mfma_f32_16x16x32_f16(
            af[mt], bf[nt], acc[mt][nt], 0, 0, 0);
    __syncthreads();
  }

  // Epilogue. C/D layout: col = l15 (n), row = quad*4 + r (m).
#pragma unroll
  for (int mt = 0; mt < FM; mt++)
#pragma unroll
    for (int nt = 0; nt < FN; nt++) {
      int n = bn + wn + nt * 16 + l15;
      float bv = bias[n];
      if (EPI == 0 && bn >= 2048) {
        // V region: pack r=0..3 (consecutive t) -> one 8-B store to V^T.
        int dg = n - 2048;
        int hh = dg >> 6, hd = dg & 63;
        int m0 = bm + wm + mt * 16 + quad * 4;
        int bb = m0 >> 11, tt = m0 & 2047;
        half2v p01 = __builtin_bit_cast(half2v,
            __builtin_amdgcn_cvt_pkrtz(acc[mt][nt][0] + bv, acc[mt][nt][1] + bv));
        half2v p23 = __builtin_bit_cast(half2v,
            __builtin_amdgcn_cvt_pkrtz(acc[mt][nt][2] + bv, acc[mt][nt][3] + bv));
        half4v pk = __builtin_shufflevector(p01, p23, 0, 1, 2, 3);
        *(half4v*)(o2 + (((size_t)(bb * H_ + hh) * 64 + hd) * 2048 + tt)) = pk;
      } else {
#pragma unroll
        for (int r = 0; r < 4; r++) {
          int m = bm + wm + mt * 16 + quad * 4 + r;
          float v = acc[mt][nt][r] + bv;
          if (EPI == 0) {
            if (bn < 1024) {
              // Q pre-scaled by 0.125 * log2(e) for base-2 softmax.
              o0[(size_t)m * 1024 + n] = (_Float16)(v * 0.180336884f);
            } else {
              o1[(size_t)m * 1024 + (n - 1024)] = (_Float16)v;    // K
            }
          } else {
            of[(size_t)m * 1024 + n] = v;
          }
        }
      }
    }
}

// ---------------------------------------------------------------------------
// MFMA flash attention (no mask, per reference). Grid (T/128, H, B), 512 thr.
// V12 = V11 + T14 async-STAGE split with double-buffered LDS and ONE barrier
// per tile: per iteration {write regs->LDS buf[it&1]; barrier; issue global
// loads for tile it+1 into regs; compute buf[it&1]}. The next tile's HBM/L2
// latency hides under ~500 cyc of MFMA+softmax, and barrier count halves.
// Safety: buf[(it+1)&1]'s last reader is compute(it-1); every wave passes
// barrier(it) (after its compute(it-1)) before any wave's write(it+1).
// LDS: 2 x (Ks[128][68] + Vs[64][132]) = 68.6 KB -- free, since the grid
// (512 blocks) already caps us at 2 blocks/CU.
// Wave w (0..7) owns q-cols qt*128 + w*16 + l15.
// S^T = K.Q^T (16x16x32, C-layout row=key col=q); P lands in the 16x16x16
// B-operand layout -> PV direct from registers. Base-2 softmax.
// ---------------------------------------------------------------------------
__global__ __launch_bounds__(512) void attn_f16_kernel(
    const _Float16* __restrict__ Qh, const _Float16* __restrict__ Kh,
    const _Float16* __restrict__ Vt, _Float16* __restrict__ Yh)
{
  __shared__ __align__(16) _Float16 Ks[2][128 * 68];   // [key][d], 136-B rows
  __shared__ __align__(16) _Float16 Vs[2][64 * 132];   // [d][t], 264-B rows
  const int t = threadIdx.x;
  const int w = t >> 6, lane = t & 63, l15 = lane & 15, quad = lane >> 4;
  const int qt = blockIdx.x, h = blockIdx.y, b = blockIdx.z;
  const int qg = qt * 128 + w * 16 + l15;
  const size_t qoff = ((size_t)(b * T_ + qg)) * C_ + h * HD_;

  half8v qf[2];
  qf[0] = *(const half8v*)(Qh + qoff + quad * 8);
  qf[1] = *(const half8v*)(Qh + qoff + 32 + quad * 8);

  f32x4 o[4];
#pragma unroll
  for (int i = 0; i < 4; i++) o[i] = (f32x4){0.f, 0.f, 0.f, 0.f};
  float m_run = -INFINITY, l_run = 0.f;

  const size_t kbase = ((size_t)b * T_) * C_ + h * HD_;
  const size_t vbase = ((size_t)(b * H_ + h)) * HD_ * 2048;

  // Fixed per-thread staging coordinates (1024 16-B chunks, 2/thread each).
  const int ks0 = t, ks1 = t + 512;
  const int krow0 = ks0 >> 3, kcp0 = ks0 & 7;
  const int krow1 = ks1 >> 3, kcp1 = ks1 & 7;
  const int vrow0 = ks0 >> 4, vcp0 = ks0 & 15;
  const int vrow1 = ks1 >> 4, vcp1 = ks1 & 15;
  const _Float16* kp0 = Kh + kbase + (size_t)krow0 * C_ + kcp0 * 8;
  const _Float16* kp1 = Kh + kbase + (size_t)krow1 * C_ + kcp1 * 8;
  const _Float16* vp0 = Vt + vbase + (size_t)vrow0 * 2048 + vcp0 * 8;
  const _Float16* vp1 = Vt + vbase + (size_t)vrow1 * 2048 + vcp1 * 8;

  // Prologue: tile 0 -> regs.
  uint4 kr0 = *(const uint4*)kp0, kr1 = *(const uint4*)kp1;
  uint4 vr0 = *(const uint4*)vp0, vr1 = *(const uint4*)vp1;

  for (int it = 0; it < 16; ++it) {
    _Float16* Ksb = Ks[it & 1];
    _Float16* Vsb = Vs[it & 1];
    // Regs -> LDS (compiler inserts vmcnt for the loads these depend on).
    *(uint4*)((char*)Ksb + krow0 * 136 + kcp0 * 16) = kr0;
    *(uint4*)((char*)Ksb + krow1 * 136 + kcp1 * 16) = kr1;
    *(uint4*)((char*)Vsb + vrow0 * 264 + vcp0 * 16) = vr0;
    *(uint4*)((char*)Vsb + vrow1 * 264 + vcp1 * 16) = vr1;
    __syncthreads();

    // Issue next tile's global loads NOW; latency hides under compute below.
    if (it + 1 < 16) {
      kp0 += 128 * (size_t)C_;  kp1 += 128 * (size_t)C_;
      vp0 += 128;               vp1 += 128;
      kr0 = *(const uint4*)kp0; kr1 = *(const uint4*)kp1;
      vr0 = *(const uint4*)vp0; vr1 = *(const uint4*)vp1;
    }

    // S^T tiles: 8 key-tiles x 2 d-steps of 16x16x32.
    f32x4 s[8];
#pragma unroll
    for (int kt = 0; kt < 8; kt++) {
      s[kt] = (f32x4){0.f, 0.f, 0.f, 0.f};
      int key = kt * 16 + l15;
#pragma unroll
      for (int ks = 0; ks < 2; ks++) {
        half8v kf = *(const half8v*)((char*)Ksb + key * 136 + (ks * 4 + quad) * 16);
        s[kt] = __builtin_amdgcn_mfma_f32_16x16x32_f16(kf, qf[ks], s[kt], 0, 0, 0);
      }
    }

    // Online softmax (base-2) over the 128 keys, per q column = l15.
    float tmax = -INFINITY;
#pragma unroll
    for (int kt = 0; kt < 8; kt++)
#pragma unroll
      for (int r = 0; r < 4; r++) tmax = fmaxf(tmax, s[kt][r]);
    tmax = fmaxf(tmax, __shfl_xor(tmax, 16));
    tmax = fmaxf(tmax, __shfl_xor(tmax, 32));
    float mnew = fmaxf(m_run, tmax);
    float alpha = __builtin_amdgcn_exp2f(m_run - mnew);

    float psum = 0.f;
    half4v pf[8];
#pragma unroll
    for (int kt = 0; kt < 8; kt++) {
      float p0 = __builtin_amdgcn_exp2f(s[kt][0] - mnew);
      float p1 = __builtin_amdgcn_exp2f(s[kt][1] - mnew);
      float p2 = __builtin_amdgcn_exp2f(s[kt][2] - mnew);
      float p3 = __builtin_amdgcn_exp2f(s[kt][3] - mnew);
      psum += (p0 + p1) + (p2 + p3);
      half2v pk01 = __builtin_bit_cast(half2v, __builtin_amdgcn_cvt_pkrtz(p0, p1));
      half2v pk23 = __builtin_bit_cast(half2v, __builtin_amdgcn_cvt_pkrtz(p2, p3));
      pf[kt] = __builtin_shufflevector(pk01, pk23, 0, 1, 2, 3);
    }
    psum += __shfl_xor(psum, 16);
    psum += __shfl_xor(psum, 32);
    l_run = l_run * alpha + psum;
    m_run = mnew;
#pragma unroll
    for (int dt = 0; dt < 4; dt++) o[dt] *= alpha;

    // PV: o^T[d][q] += V^T x P, 4 d-tiles x 8 key-tiles of 16x16x16.
#pragma unroll
    for (int dt = 0; dt < 4; dt++) {
      int d = dt * 16 + l15;
#pragma unroll
      for (int kt = 0; kt < 8; kt++) {
        half4v vf = *(const half4v*)((char*)Vsb + d * 264 + kt * 32 + quad * 8);
        o[dt] = __builtin_amdgcn_mfma_f32_16x16x16f16(vf, pf[kt], o[dt], 0, 0, 0);
      }
    }
  }

  float inv = 1.0f / l_run;
#pragma unroll
  for (int dt = 0; dt < 4; dt++) {
    half4v yv;
#pragma unroll
    for (int r = 0; r < 4; r++) yv[r] = (_Float16)(o[dt][r] * inv);
    *(half4v*)(Yh + qoff + dt * 16 + quad * 4) = yv;  // row q, cols h*64+d..
  }
}

// ---------------------------------------------------------------------------
extern "C" void kernel_launch(void* const* d_in, const int* in_sizes, int n_in,
                              void* d_out, int out_size, void* d_ws, size_t ws_size,
                              hipStream_t stream) {
  const float* x  = (const float*)d_in[0];
  const float* Wq = (const float*)d_in[1];
  const float* bq = (const float*)d_in[2];
  const float* Wk = (const float*)d_in[3];
  const float* bk = (const float*)d_in[4];
  const float* Wv = (const float*)d_in[5];
  const float* bv = (const float*)d_in[6];
  const float* Wo = (const float*)d_in[7];
  const float* bo = (const float*)d_in[8];
  float* out = (float*)d_out;

  // Workspace carve-up (bytes). Each f16 plane M_*C_ = 8 MB.
  char* ws = (char*)d_ws;
  _Float16* xh   = (_Float16*)(ws);                        // 8 MB
  _Float16* Qh   = (_Float16*)(ws + (((size_t)8)  << 20)); // 8 MB
  _Float16* Kh   = (_Float16*)(ws + (((size_t)16) << 20)); // 8 MB
  _Float16* Vt   = (_Float16*)(ws + (((size_t)24) << 20)); // 8 MB  [b,h,d,t]
  _Float16* Yh   = (_Float16*)(ws + (((size_t)32) << 20)); // 8 MB
  _Float16* Wt3  = (_Float16*)(ws + (((size_t)40) << 20)); // 6 MB  [3072][1024]
  _Float16* Wot  = (_Float16*)(ws + (((size_t)46) << 20)); // 2 MB  [1024][1024]
  float*    b3   = (float*)   (ws + (((size_t)48) << 20)); // 12 KB

  prep_kernel<<<8204, 256, 0, stream>>>(x, Wq, Wk, Wv, Wo, bq, bk, bv,
                                        xh, Wt3, Wot, b3);

  // Fused QKV projection: [4096,1024] @ [1024,3072] -> Q,K (f16) + V^T (f16).
  gemm_f16_kernel<128, 128, 0><<<dim3(24, 32), 256, 0, stream>>>(
      xh, Wt3, b3, Qh, Kh, Vt, nullptr);

  attn_f16_kernel<<<dim3(T_ / 128, H_, B_), 512, 0, stream>>>(Qh, Kh, Vt, Yh);

  // Output projection: Yh @ Wot^T + bo -> fp32 out.
  gemm_f16_kernel<64, 128, 1><<<dim3(8, 64), 256, 0, stream>>>(
      Yh, Wot, bo, nullptr, nullptr, nullptr, out);
}

// Round 3
// 305.138 us; speedup vs baseline: 1.0107x; 1.0107x over previous
//
#include <hip/hip_runtime.h>
#include <math.h>

#define B_ 2
#define T_ 2048
#define C_ 1024
#define H_ 16
#define HD_ 64
#define M_ (B_*T_)

typedef _Float16 half2v __attribute__((ext_vector_type(2)));
typedef _Float16 half4v __attribute__((ext_vector_type(4)));
typedef _Float16 half8v __attribute__((ext_vector_type(8)));
typedef float f32x4 __attribute__((ext_vector_type(4)));

#define GLD_LDS(gp, lp) \
  __builtin_amdgcn_global_load_lds( \
      (const __attribute__((address_space(1))) void*)(gp), \
      (__attribute__((address_space(3))) void*)(lp), 16, 0, 0)

// ---------------------------------------------------------------------------
// Fused prep: fp32->f16 cast of x (blocks 0..4095), 4 weight transposes
// (blocks 4096..8191), bias concat (blocks 8192..8203). One launch.
// ---------------------------------------------------------------------------
__global__ __launch_bounds__(256) void prep_kernel(
    const float* __restrict__ x,
    const float* __restrict__ Wq, const float* __restrict__ Wk,
    const float* __restrict__ Wv, const float* __restrict__ Wo,
    const float* __restrict__ bq, const float* __restrict__ bk,
    const float* __restrict__ bv,
    _Float16* __restrict__ xh, _Float16* __restrict__ Wt3,
    _Float16* __restrict__ Wot, float* __restrict__ b3)
{
  __shared__ float tile[32][33];
  const int blk = blockIdx.x, thr = threadIdx.x;
  if (blk < 4096) {
    int i = blk * 256 + thr;
    float4 v = ((const float4*)x)[i];
    half4v h; h[0] = (_Float16)v.x; h[1] = (_Float16)v.y;
    h[2] = (_Float16)v.z; h[3] = (_Float16)v.w;
    ((half4v*)xh)[i] = h;
  } else if (blk < 8192) {
    int zz = (blk - 4096) >> 10;      // which W
    int bxy = (blk - 4096) & 1023;
    const float* W; _Float16* Wt;
    switch (zz) {
      case 0:  W = Wq; Wt = Wt3; break;
      case 1:  W = Wk; Wt = Wt3 + (size_t)1024 * 1024; break;
      case 2:  W = Wv; Wt = Wt3 + (size_t)2048 * 1024; break;
      default: W = Wo; Wt = Wot; break;
    }
    const int n0 = (bxy & 31) * 32, k0 = (bxy >> 5) * 32;
    const int tx = thr & 31, ty = thr >> 5;  // 32 x 8
#pragma unroll
    for (int r = 0; r < 4; r++) {
      int k = ty + r * 8;
      tile[k][tx] = W[(size_t)(k0 + k) * C_ + n0 + tx];
    }
    __syncthreads();
#pragma unroll
    for (int r = 0; r < 4; r++) {
      int n = ty + r * 8;
      Wt[(size_t)(n0 + n) * C_ + k0 + tx] = (_Float16)tile[tx][n];
    }
  } else {
    int i = (blk - 8192) * 256 + thr;  // 0..3071
    const float* s = (i < 1024) ? bq : ((i < 2048) ? bk : bv);
    b3[i] = s[i & 1023];
  }
}

// ---------------------------------------------------------------------------
// f16 MFMA GEMM: Out[M,N] = A[M,1024] @ Wt[N,1024]^T + bias.
// BK=32, 256 threads = 4 waves (2x2); wave tile (BM/2)x(BN/2).
// Staging via global_load_lds width=16 (m97 pattern).
// EPI 0: fused QKV epilogue. Q (scaled 0.125*log2e) and K: plain 2-B stores
//   (4 rows x 32-B runs per wave-store). V: r=0..3 are 4 CONSECUTIVE t in
//   Vt[b,h,d,t] -> packed into ONE 8-B store (4x fewer instrs, 4x better
//   line locality than the r9 2-B scatter).
// EPI 1: fp32 out + bias (of).
// ---------------------------------------------------------------------------
template <int BM, int BN, int EPI>
__global__ __launch_bounds__(256) void gemm_f16_kernel(
    const _Float16* __restrict__ A, const _Float16* __restrict__ Bw,
    const float* __restrict__ bias,
    _Float16* __restrict__ o0, _Float16* __restrict__ o1,
    _Float16* __restrict__ o2, float* __restrict__ of)
{
  constexpr int FM = BM / 32, FN = BN / 32;
  __shared__ __align__(16) _Float16 As[BM * 32];
  __shared__ __align__(16) _Float16 Bs[BN * 32];
  const int t = threadIdx.x;
  const int w = t >> 6, lane = t & 63, l15 = lane & 15, quad = lane >> 4;
  const int wm = (w & 1) * (BM / 2), wn = (w >> 1) * (BN / 2);
  const int bm = blockIdx.y * BM, bn = blockIdx.x * BN;
  const int lrow = lane >> 2, lcol = (lane & 3) * 8;  // staging: 16 rows/call

  f32x4 acc[FM][FN];
#pragma unroll
  for (int i = 0; i < FM; i++)
#pragma unroll
    for (int j = 0; j < FN; j++) acc[i][j] = (f32x4){0.f, 0.f, 0.f, 0.f};

  for (int k0 = 0; k0 < 1024; k0 += 32) {
#pragma unroll
    for (int i = 0; i < BM / 64; i++) {
      int ca = w + 4 * i;
      int row = ca * 16 + lrow;
      GLD_LDS(A + (size_t)(bm + row) * 1024 + k0 + lcol, As + ca * 512);
    }
#pragma unroll
    for (int i = 0; i < BN / 64; i++) {
      int cb = w + 4 * i;
      int row = cb * 16 + lrow;
      GLD_LDS(Bw + (size_t)(bn + row) * 1024 + k0 + lcol, Bs + cb * 512);
    }
    __syncthreads();

    half8v af[FM], bf[FN];
#pragma unroll
    for (int mt = 0; mt < FM; mt++)
      af[mt] = *(const half8v*)(As + (wm + mt * 16 + l15) * 32 + quad * 8);
#pragma unroll
    for (int nt = 0; nt < FN; nt++)
      bf[nt] = *(const half8v*)(Bs + (wn + nt * 16 + l15) * 32 + quad * 8);
#pragma unroll
    for (int mt = 0; mt < FM; mt++)
#pragma unroll
      for (int nt = 0; nt < FN; nt++)
        acc[mt][nt] = __builtin_amdgcn_mfma_f32_16x16x32_f16(
            af[mt], bf[nt], acc[mt][nt], 0, 0, 0);
    __syncthreads();
  }

  // Epilogue. C/D layout: col = l15 (n), row = quad*4 + r (m).
#pragma unroll
  for (int mt = 0; mt < FM; mt++)
#pragma unroll
    for (int nt = 0; nt < FN; nt++) {
      int n = bn + wn + nt * 16 + l15;
      float bv = bias[n];
      if (EPI == 0 && bn >= 2048) {
        // V region: pack r=0..3 (consecutive t) -> one 8-B store to V^T.
        int dg = n - 2048;
        int hh = dg >> 6, hd = dg & 63;
        int m0 = bm + wm + mt * 16 + quad * 4;
        int bb = m0 >> 11, tt = m0 & 2047;
        half2v p01 = __builtin_bit_cast(half2v,
            __builtin_amdgcn_cvt_pkrtz(acc[mt][nt][0] + bv, acc[mt][nt][1] + bv));
        half2v p23 = __builtin_bit_cast(half2v,
            __builtin_amdgcn_cvt_pkrtz(acc[mt][nt][2] + bv, acc[mt][nt][3] + bv));
        half4v pk = __builtin_shufflevector(p01, p23, 0, 1, 2, 3);
        *(half4v*)(o2 + (((size_t)(bb * H_ + hh) * 64 + hd) * 2048 + tt)) = pk;
      } else {
#pragma unroll
        for (int r = 0; r < 4; r++) {
          int m = bm + wm + mt * 16 + quad * 4 + r;
          float v = acc[mt][nt][r] + bv;
          if (EPI == 0) {
            if (bn < 1024) {
              // Q pre-scaled by 0.125 * log2(e) for base-2 softmax.
              o0[(size_t)m * 1024 + n] = (_Float16)(v * 0.180336884f);
            } else {
              o1[(size_t)m * 1024 + (n - 1024)] = (_Float16)v;    // K
            }
          } else {
            of[(size_t)m * 1024 + n] = v;
          }
        }
      }
    }
}

// ---------------------------------------------------------------------------
// MFMA flash attention (no mask, per reference). Grid (T/128, H, B), 512 thr.
// V13: round-2 post-mortem showed 68.6 KB LDS dropped co-residency to
// 1 block/CU (occupancy 36%->23%, dur 2.6x) -- the async split was never at
// fault. V13 keeps the T14 async split (one barrier/tile, prefetch next
// tile's K/V right after the barrier, regs->LDS at top of next iteration)
// but with KVBLK=64 double-buffered: LDS = 2*(Ks[64][68]+Vs[64][68]) =
// 34.8 KB == round-1's proven 2-blocks/CU footprint. Per thread per tile:
// 1 K-load + 1 V-load + 2 ds_writes. 32 tiles, 32 barriers (same count as
// round 1) but load latency now hides under the previous tile's compute.
// Buffer safety: write(it)->buf[it&1] last read by compute(it-2), and
// barrier(it-1) orders all waves' compute(it-2) before any write(it).
// Wave w (0..7) owns q-cols qt*128 + w*16 + l15.
// S^T = K.Q^T (16x16x32, C-layout row=key col=q); P lands in the 16x16x16
// B-operand layout -> PV direct from registers. Base-2 softmax.
// ---------------------------------------------------------------------------
__global__ __launch_bounds__(512) void attn_f16_kernel(
    const _Float16* __restrict__ Qh, const _Float16* __restrict__ Kh,
    const _Float16* __restrict__ Vt, _Float16* __restrict__ Yh)
{
  __shared__ __align__(16) _Float16 Ks[2][64 * 68];   // [key][d], 136-B rows
  __shared__ __align__(16) _Float16 Vs[2][64 * 68];   // [d][t], 136-B rows
  const int t = threadIdx.x;
  const int w = t >> 6, lane = t & 63, l15 = lane & 15, quad = lane >> 4;
  const int qt = blockIdx.x, h = blockIdx.y, b = blockIdx.z;
  const int qg = qt * 128 + w * 16 + l15;
  const size_t qoff = ((size_t)(b * T_ + qg)) * C_ + h * HD_;

  half8v qf[2];
  qf[0] = *(const half8v*)(Qh + qoff + quad * 8);
  qf[1] = *(const half8v*)(Qh + qoff + 32 + quad * 8);

  f32x4 o[4];
#pragma unroll
  for (int i = 0; i < 4; i++) o[i] = (f32x4){0.f, 0.f, 0.f, 0.f};
  float m_run = -INFINITY, l_run = 0.f;

  const size_t kbase = ((size_t)b * T_) * C_ + h * HD_;
  const size_t vbase = ((size_t)(b * H_ + h)) * HD_ * 2048;

  // Fixed per-thread staging coords: 512 16-B chunks per tile per matrix,
  // 512 threads -> 1 chunk each. K: row=key, V: row=d; cp = 16-B column.
  const int srow = t >> 3, scp = t & 7;
  const int lds_off = srow * 136 + scp * 16;      // byte offset within a tile
  const _Float16* kp = Kh + kbase + (size_t)srow * C_ + scp * 8;
  const _Float16* vp = Vt + vbase + (size_t)srow * 2048 + scp * 8;

  // Prologue: tile 0 -> regs.
  uint4 kr = *(const uint4*)kp;
  uint4 vr = *(const uint4*)vp;

  for (int it = 0; it < 32; ++it) {
    _Float16* Ksb = Ks[it & 1];
    _Float16* Vsb = Vs[it & 1];
    // Regs -> LDS (compiler inserts the vmcnt for the producing loads).
    *(uint4*)((char*)Ksb + lds_off) = kr;
    *(uint4*)((char*)Vsb + lds_off) = vr;
    __syncthreads();

    // Issue next tile's global loads NOW; latency hides under compute below.
    if (it + 1 < 32) {
      kp += (size_t)64 * C_;
      vp += 64;
      kr = *(const uint4*)kp;
      vr = *(const uint4*)vp;
    }

    // S^T tiles: 4 key-tiles x 2 d-steps of 16x16x32.
    f32x4 s[4];
#pragma unroll
    for (int kt = 0; kt < 4; kt++) {
      s[kt] = (f32x4){0.f, 0.f, 0.f, 0.f};
      int key = kt * 16 + l15;
#pragma unroll
      for (int ks = 0; ks < 2; ks++) {
        half8v kf = *(const half8v*)((char*)Ksb + key * 136 + (ks * 4 + quad) * 16);
        s[kt] = __builtin_amdgcn_mfma_f32_16x16x32_f16(kf, qf[ks], s[kt], 0, 0, 0);
      }
    }

    // Online softmax (base-2) over the 64 keys, per q column = l15.
    float tmax = -INFINITY;
#pragma unroll
    for (int kt = 0; kt < 4; kt++)
#pragma unroll
      for (int r = 0; r < 4; r++) tmax = fmaxf(tmax, s[kt][r]);
    tmax = fmaxf(tmax, __shfl_xor(tmax, 16));
    tmax = fmaxf(tmax, __shfl_xor(tmax, 32));
    float mnew = fmaxf(m_run, tmax);
    float alpha = __builtin_amdgcn_exp2f(m_run - mnew);

    float psum = 0.f;
    half4v pf[4];
#pragma unroll
    for (int kt = 0; kt < 4; kt++) {
      float p0 = __builtin_amdgcn_exp2f(s[kt][0] - mnew);
      float p1 = __builtin_amdgcn_exp2f(s[kt][1] - mnew);
      float p2 = __builtin_amdgcn_exp2f(s[kt][2] - mnew);
      float p3 = __builtin_amdgcn_exp2f(s[kt][3] - mnew);
      psum += (p0 + p1) + (p2 + p3);
      half2v pk01 = __builtin_bit_cast(half2v, __builtin_amdgcn_cvt_pkrtz(p0, p1));
      half2v pk23 = __builtin_bit_cast(half2v, __builtin_amdgcn_cvt_pkrtz(p2, p3));
      pf[kt] = __builtin_shufflevector(pk01, pk23, 0, 1, 2, 3);
    }
    psum += __shfl_xor(psum, 16);
    psum += __shfl_xor(psum, 32);
    l_run = l_run * alpha + psum;
    m_run = mnew;
#pragma unroll
    for (int dt = 0; dt < 4; dt++) o[dt] *= alpha;

    // PV: o^T[d][q] += V^T x P, 4 d-tiles x 4 key-tiles of 16x16x16.
#pragma unroll
    for (int dt = 0; dt < 4; dt++) {
      int d = dt * 16 + l15;
#pragma unroll
      for (int kt = 0; kt < 4; kt++) {
        half4v vf = *(const half4v*)((char*)Vsb + d * 136 + kt * 32 + quad * 8);
        o[dt] = __builtin_amdgcn_mfma_f32_16x16x16f16(vf, pf[kt], o[dt], 0, 0, 0);
      }
    }
  }

  float inv = 1.0f / l_run;
#pragma unroll
  for (int dt = 0; dt < 4; dt++) {
    half4v yv;
#pragma unroll
    for (int r = 0; r < 4; r++) yv[r] = (_Float16)(o[dt][r] * inv);
    *(half4v*)(Yh + qoff + dt * 16 + quad * 4) = yv;  // row q, cols h*64+d..
  }
}

// ---------------------------------------------------------------------------
extern "C" void kernel_launch(void* const* d_in, const int* in_sizes, int n_in,
                              void* d_out, int out_size, void* d_ws, size_t ws_size,
                              hipStream_t stream) {
  const float* x  = (const float*)d_in[0];
  const float* Wq = (const float*)d_in[1];
  const float* bq = (const float*)d_in[2];
  const float* Wk = (const float*)d_in[3];
  const float* bk = (const float*)d_in[4];
  const float* Wv = (const float*)d_in[5];
  const float* bv = (const float*)d_in[6];
  const float* Wo = (const float*)d_in[7];
  const float* bo = (const float*)d_in[8];
  float* out = (float*)d_out;

  // Workspace carve-up (bytes). Each f16 plane M_*C_ = 8 MB.
  char* ws = (char*)d_ws;
  _Float16* xh   = (_Float16*)(ws);                        // 8 MB
  _Float16* Qh   = (_Float16*)(ws + (((size_t)8)  << 20)); // 8 MB
  _Float16* Kh   = (_Float16*)(ws + (((size_t)16) << 20)); // 8 MB
  _Float16* Vt   = (_Float16*)(ws + (((size_t)24) << 20)); // 8 MB  [b,h,d,t]
  _Float16* Yh   = (_Float16*)(ws + (((size_t)32) << 20)); // 8 MB
  _Float16* Wt3  = (_Float16*)(ws + (((size_t)40) << 20)); // 6 MB  [3072][1024]
  _Float16* Wot  = (_Float16*)(ws + (((size_t)46) << 20)); // 2 MB  [1024][1024]
  float*    b3   = (float*)   (ws + (((size_t)48) << 20)); // 12 KB

  prep_kernel<<<8204, 256, 0, stream>>>(x, Wq, Wk, Wv, Wo, bq, bk, bv,
                                        xh, Wt3, Wot, b3);

  // Fused QKV projection: [4096,1024] @ [1024,3072] -> Q,K (f16) + V^T (f16).
  gemm_f16_kernel<128, 128, 0><<<dim3(24, 32), 256, 0, stream>>>(
      xh, Wt3, b3, Qh, Kh, Vt, nullptr);

  attn_f16_kernel<<<dim3(T_ / 128, H_, B_), 512, 0, stream>>>(Qh, Kh, Vt, Yh);

  // Output projection: Yh @ Wot^T + bo -> fp32 out.
  gemm_f16_kernel<64, 128, 1><<<dim3(8, 64), 256, 0, stream>>>(
      Yh, Wot, bo, nullptr, nullptr, nullptr, out);
}

// Round 5
// 212.791 us; speedup vs baseline: 1.4493x; 1.4340x over previous
//
#include <hip/hip_runtime.h>
#include <math.h>

#define B_ 2
#define T_ 2048
#define C_ 1024
#define H_ 16
#define HD_ 64
#define M_ (B_*T_)

typedef _Float16 half2v __attribute__((ext_vector_type(2)));
typedef _Float16 half4v __attribute__((ext_vector_type(4)));
typedef _Float16 half8v __attribute__((ext_vector_type(8)));
typedef float f32x4 __attribute__((ext_vector_type(4)));

#define GLD_LDS(gp, lp) \
  __builtin_amdgcn_global_load_lds( \
      (const __attribute__((address_space(1))) void*)(gp), \
      (__attribute__((address_space(3))) void*)(lp), 16, 0, 0)

// ---------------------------------------------------------------------------
// Fused prep: fp32->f16 cast of x (blocks 0..4095), 4 weight transposes
// (blocks 4096..8191), bias concat (blocks 8192..8203). One launch.
// ---------------------------------------------------------------------------
__global__ __launch_bounds__(256) void prep_kernel(
    const float* __restrict__ x,
    const float* __restrict__ Wq, const float* __restrict__ Wk,
    const float* __restrict__ Wv, const float* __restrict__ Wo,
    const float* __restrict__ bq, const float* __restrict__ bk,
    const float* __restrict__ bv,
    _Float16* __restrict__ xh, _Float16* __restrict__ Wt3,
    _Float16* __restrict__ Wot, float* __restrict__ b3)
{
  __shared__ float tile[32][33];
  const int blk = blockIdx.x, thr = threadIdx.x;
  if (blk < 4096) {
    int i = blk * 256 + thr;
    float4 v = ((const float4*)x)[i];
    half4v h; h[0] = (_Float16)v.x; h[1] = (_Float16)v.y;
    h[2] = (_Float16)v.z; h[3] = (_Float16)v.w;
    ((half4v*)xh)[i] = h;
  } else if (blk < 8192) {
    int zz = (blk - 4096) >> 10;      // which W
    int bxy = (blk - 4096) & 1023;
    const float* W; _Float16* Wt;
    switch (zz) {
      case 0:  W = Wq; Wt = Wt3; break;
      case 1:  W = Wk; Wt = Wt3 + (size_t)1024 * 1024; break;
      case 2:  W = Wv; Wt = Wt3 + (size_t)2048 * 1024; break;
      default: W = Wo; Wt = Wot; break;
    }
    const int n0 = (bxy & 31) * 32, k0 = (bxy >> 5) * 32;
    const int tx = thr & 31, ty = thr >> 5;  // 32 x 8
#pragma unroll
    for (int r = 0; r < 4; r++) {
      int k = ty + r * 8;
      tile[k][tx] = W[(size_t)(k0 + k) * C_ + n0 + tx];
    }
    __syncthreads();
#pragma unroll
    for (int r = 0; r < 4; r++) {
      int n = ty + r * 8;
      Wt[(size_t)(n0 + n) * C_ + k0 + tx] = (_Float16)tile[tx][n];
    }
  } else {
    int i = (blk - 8192) * 256 + thr;  // 0..3071
    const float* s = (i < 1024) ? bq : ((i < 2048) ? bk : bv);
    b3[i] = s[i & 1023];
  }
}

// ---------------------------------------------------------------------------
// f16 MFMA GEMM: Out[M,N] = A[M,1024] @ Wt[N,1024]^T + bias.
// BK=32, 256 threads = 4 waves (2x2); wave tile (BM/2)x(BN/2).
// Staging via global_load_lds width=16 (m97 pattern).
// EPI 0: fused QKV epilogue. Q (scaled 0.125*log2e) and K: plain 2-B stores.
// V: packed 8-B stores to V^T.  EPI 1: fp32 out + bias (of).
// ---------------------------------------------------------------------------
template <int BM, int BN, int EPI>
__global__ __launch_bounds__(256) void gemm_f16_kernel(
    const _Float16* __restrict__ A, const _Float16* __restrict__ Bw,
    const float* __restrict__ bias,
    _Float16* __restrict__ o0, _Float16* __restrict__ o1,
    _Float16* __restrict__ o2, float* __restrict__ of)
{
  constexpr int FM = BM / 32, FN = BN / 32;
  __shared__ __align__(16) _Float16 As[BM * 32];
  __shared__ __align__(16) _Float16 Bs[BN * 32];
  const int t = threadIdx.x;
  const int w = t >> 6, lane = t & 63, l15 = lane & 15, quad = lane >> 4;
  const int wm = (w & 1) * (BM / 2), wn = (w >> 1) * (BN / 2);
  const int bm = blockIdx.y * BM, bn = blockIdx.x * BN;
  const int lrow = lane >> 2, lcol = (lane & 3) * 8;  // staging: 16 rows/call

  f32x4 acc[FM][FN];
#pragma unroll
  for (int i = 0; i < FM; i++)
#pragma unroll
    for (int j = 0; j < FN; j++) acc[i][j] = (f32x4){0.f, 0.f, 0.f, 0.f};

  for (int k0 = 0; k0 < 1024; k0 += 32) {
#pragma unroll
    for (int i = 0; i < BM / 64; i++) {
      int ca = w + 4 * i;
      int row = ca * 16 + lrow;
      GLD_LDS(A + (size_t)(bm + row) * 1024 + k0 + lcol, As + ca * 512);
    }
#pragma unroll
    for (int i = 0; i < BN / 64; i++) {
      int cb = w + 4 * i;
      int row = cb * 16 + lrow;
      GLD_LDS(Bw + (size_t)(bn + row) * 1024 + k0 + lcol, Bs + cb * 512);
    }
    __syncthreads();

    half8v af[FM], bf[FN];
#pragma unroll
    for (int mt = 0; mt < FM; mt++)
      af[mt] = *(const half8v*)(As + (wm + mt * 16 + l15) * 32 + quad * 8);
#pragma unroll
    for (int nt = 0; nt < FN; nt++)
      bf[nt] = *(const half8v*)(Bs + (wn + nt * 16 + l15) * 32 + quad * 8);
#pragma unroll
    for (int mt = 0; mt < FM; mt++)
#pragma unroll
      for (int nt = 0; nt < FN; nt++)
        acc[mt][nt] = __builtin_amdgcn_mfma_f32_16x16x32_f16(
            af[mt], bf[nt], acc[mt][nt], 0, 0, 0);
    __syncthreads();
  }

  // Epilogue. C/D layout: col = l15 (n), row = quad*4 + r (m).
#pragma unroll
  for (int mt = 0; mt < FM; mt++)
#pragma unroll
    for (int nt = 0; nt < FN; nt++) {
      int n = bn + wn + nt * 16 + l15;
      float bv = bias[n];
      if (EPI == 0 && bn >= 2048) {
        // V region: pack r=0..3 (consecutive t) -> one 8-B store to V^T.
        int dg = n - 2048;
        int hh = dg >> 6, hd = dg & 63;
        int m0 = bm + wm + mt * 16 + quad * 4;
        int bb = m0 >> 11, tt = m0 & 2047;
        half2v p01 = __builtin_bit_cast(half2v,
            __builtin_amdgcn_cvt_pkrtz(acc[mt][nt][0] + bv, acc[mt][nt][1] + bv));
        half2v p23 = __builtin_bit_cast(half2v,
            __builtin_amdgcn_cvt_pkrtz(acc[mt][nt][2] + bv, acc[mt][nt][3] + bv));
        half4v pk = __builtin_shufflevector(p01, p23, 0, 1, 2, 3);
        *(half4v*)(o2 + (((size_t)(bb * H_ + hh) * 64 + hd) * 2048 + tt)) = pk;
      } else {
#pragma unroll
        for (int r = 0; r < 4; r++) {
          int m = bm + wm + mt * 16 + quad * 4 + r;
          float v = acc[mt][nt][r] + bv;
          if (EPI == 0) {
            if (bn < 1024) {
              // Q pre-scaled by 0.125 * log2(e) for base-2 softmax.
              o0[(size_t)m * 1024 + n] = (_Float16)(v * 0.180336884f);
            } else {
              o1[(size_t)m * 1024 + (n - 1024)] = (_Float16)v;    // K
            }
          } else {
            of[(size_t)m * 1024 + n] = v;
          }
        }
      }
    }
}

// ---------------------------------------------------------------------------
// MFMA flash attention (no mask, per reference). Grid (T/128, H, B), 512 thr.
// V14 = round-1 V11 frame EXACTLY (stage -> barrier -> compute -> barrier;
// async/single-barrier restructures lose 2.4-2.6x: rounds 2-3 + prior r7/r9),
// with three within-structure changes:
//  (a) PV upgraded 16x16x16 -> 16x16x32 via key permutation: the S^T A-read
//      picks key = 32p + quad*8 + r (+4 for odd tile), so concat(pf[2p],
//      pf[2p+1]) IS the x32 B-operand and V^T is read as one b128. Halves PV
//      MFMA instruction count at same FLOP (x16 shape issues at x32 cost).
//      Softmax is permutation-invariant; C/D layout unchanged.
//  (b) bijective XCD swizzle: 4 complete (b,h) K/V sets (2 MB) per XCD L2
//      instead of round-robin spray (~4x K/V HBM duplication, HBM-latency
//      staging) -> L2-latency staging, FETCH ~70 -> ~30 MB.
//  (c) s_setprio(1) around MFMA clusters (T5, attn-proven +4-7%).
// LDS: Ks[128][68] + Vs[64][132] = 34.3 KB (2 blocks/CU proven).
// Wave w (0..7) owns q-cols qt*128 + w*16 + l15. Base-2 softmax.
// ---------------------------------------------------------------------------
__global__ __launch_bounds__(512) void attn_f16_kernel(
    const _Float16* __restrict__ Qh, const _Float16* __restrict__ Kh,
    const _Float16* __restrict__ Vt, _Float16* __restrict__ Yh)
{
  __shared__ __align__(16) _Float16 Ks[128 * 68];   // [key][d], 136-B rows
  __shared__ __align__(16) _Float16 Vs[64 * 132];   // [d][t], 264-B rows
  const int t = threadIdx.x;
  const int w = t >> 6, lane = t & 63, l15 = lane & 15, quad = lane >> 4;
  // XCD-aware bijective remap of the 512 linear block ids (x fastest):
  // work id swz = (lin%8)*64 + lin/8 -> 64-consecutive-work chunks per XCD,
  // each chunk = 4 complete (b,h) groups (their K/V stay in one L2).
  const int lin = blockIdx.x + 16 * blockIdx.y + 256 * blockIdx.z;
  const int swz = (lin & 7) * 64 + (lin >> 3);
  const int qt = swz & 15, h = (swz >> 4) & 15, b = swz >> 8;
  const int qg = qt * 128 + w * 16 + l15;
  const size_t qoff = ((size_t)(b * T_ + qg)) * C_ + h * HD_;

  half8v qf[2];
  qf[0] = *(const half8v*)(Qh + qoff + quad * 8);
  qf[1] = *(const half8v*)(Qh + qoff + 32 + quad * 8);

  f32x4 o[4];
#pragma unroll
  for (int i = 0; i < 4; i++) o[i] = (f32x4){0.f, 0.f, 0.f, 0.f};
  float m_run = -INFINITY, l_run = 0.f;

  const size_t kbase = ((size_t)b * T_) * C_ + h * HD_;
  const size_t vbase = ((size_t)(b * H_ + h)) * HD_ * 2048;

  // Permuted S^T key-row base (bytes): key = 32p + quad'*8 + r (+4 odd tile),
  // where for the A-operand read quad' = l15>>2, r = l15&3.
  const int kprow = ((l15 >> 2) * 8 + (l15 & 3)) * 136;

  for (int kt0 = 0; kt0 < T_; kt0 += 128) {
    // Stage K: 128 keys x 64 d = 1024 16-B chunks (2 per thread).
#pragma unroll
    for (int i = 0; i < 2; i++) {
      int slot = t + i * 512;          // 0..1023
      int row = slot >> 3, cp = slot & 7;
      *(uint4*)((char*)Ks + row * 136 + cp * 16) =
          *(const uint4*)(Kh + kbase + (size_t)(kt0 + row) * C_ + cp * 8);
    }
    // Stage V^T: 64 d x 128 t = 1024 16-B chunks (2 per thread).
#pragma unroll
    for (int i = 0; i < 2; i++) {
      int slot = t + i * 512;          // 0..1023
      int row = slot >> 4, cp = slot & 15;
      *(uint4*)((char*)Vs + row * 264 + cp * 16) =
          *(const uint4*)(Vt + vbase + (size_t)row * 2048 + kt0 + cp * 8);
    }
    __syncthreads();

    // S^T tiles: 8 key-tiles x 2 d-steps of 16x16x32, permuted key rows.
    // Tile kt covers keys {32*(kt>>1) + q*8 + (kt&1)*4 + r : q,r in [0,4)}.
    f32x4 s[8];
    __builtin_amdgcn_s_setprio(1);
#pragma unroll
    for (int kt = 0; kt < 8; kt++) {
      s[kt] = (f32x4){0.f, 0.f, 0.f, 0.f};
      const int koff = (kt >> 1) * (32 * 136) + (kt & 1) * (4 * 136);
#pragma unroll
      for (int ks = 0; ks < 2; ks++) {
        half8v kf = *(const half8v*)((char*)Ks + kprow + koff + (ks * 4 + quad) * 16);
        s[kt] = __builtin_amdgcn_mfma_f32_16x16x32_f16(kf, qf[ks], s[kt], 0, 0, 0);
      }
    }
    __builtin_amdgcn_s_setprio(0);

    // Online softmax (base-2) over the 128 keys, per q column = l15.
    // (Key permutation is irrelevant to max/sum.)
    float tmax = -INFINITY;
#pragma unroll
    for (int kt = 0; kt < 8; kt++)
#pragma unroll
      for (int r = 0; r < 4; r++) tmax = fmaxf(tmax, s[kt][r]);
    tmax = fmaxf(tmax, __shfl_xor(tmax, 16));
    tmax = fmaxf(tmax, __shfl_xor(tmax, 32));
    float mnew = fmaxf(m_run, tmax);
    float alpha = __builtin_amdgcn_exp2f(m_run - mnew);

    float psum = 0.f;
    half4v pf[8];
#pragma unroll
    for (int kt = 0; kt < 8; kt++) {
      float p0 = __builtin_amdgcn_exp2f(s[kt][0] - mnew);
      float p1 = __builtin_amdgcn_exp2f(s[kt][1] - mnew);
      float p2 = __builtin_amdgcn_exp2f(s[kt][2] - mnew);
      float p3 = __builtin_amdgcn_exp2f(s[kt][3] - mnew);
      psum += (p0 + p1) + (p2 + p3);
      half2v pk01 = __builtin_bit_cast(half2v, __builtin_amdgcn_cvt_pkrtz(p0, p1));
      half2v pk23 = __builtin_bit_cast(half2v, __builtin_amdgcn_cvt_pkrtz(p2, p3));
      pf[kt] = __builtin_shufflevector(pk01, pk23, 0, 1, 2, 3);
    }
    psum += __shfl_xor(psum, 16);
    psum += __shfl_xor(psum, 32);
    l_run = l_run * alpha + psum;
    m_run = mnew;
#pragma unroll
    for (int dt = 0; dt < 4; dt++) o[dt] *= alpha;

    // PV: o^T[d][q] += V^T x P, 4 d-tiles x 4 key-groups of 16x16x32.
    // Lane quad q holds P for keys 32p + q*8 + (0..3 | 4..7) in pf[2p|2p+1];
    // concat = x32 B-operand. V^T A-operand: keys 32p + quad*8.. as b128.
    __builtin_amdgcn_s_setprio(1);
#pragma unroll
    for (int dt = 0; dt < 4; dt++) {
      int d = dt * 16 + l15;
#pragma unroll
      for (int p = 0; p < 4; p++) {
        half8v vf = *(const half8v*)((char*)Vs + d * 264 + p * 64 + quad * 16);
        half8v pf8 = __builtin_shufflevector(pf[2 * p], pf[2 * p + 1],
                                             0, 1, 2, 3, 4, 5, 6, 7);
        o[dt] = __builtin_amdgcn_mfma_f32_16x16x32_f16(vf, pf8, o[dt], 0, 0, 0);
      }
    }
    __builtin_amdgcn_s_setprio(0);
    __syncthreads();
  }

  float inv = 1.0f / l_run;
#pragma unroll
  for (int dt = 0; dt < 4; dt++) {
    half4v yv;
#pragma unroll
    for (int r = 0; r < 4; r++) yv[r] = (_Float16)(o[dt][r] * inv);
    *(half4v*)(Yh + qoff + dt * 16 + quad * 4) = yv;  // row q, cols h*64+d..
  }
}

// ---------------------------------------------------------------------------
extern "C" void kernel_launch(void* const* d_in, const int* in_sizes, int n_in,
                              void* d_out, int out_size, void* d_ws, size_t ws_size,
                              hipStream_t stream) {
  const float* x  = (const float*)d_in[0];
  const float* Wq = (const float*)d_in[1];
  const float* bq = (const float*)d_in[2];
  const float* Wk = (const float*)d_in[3];
  const float* bk = (const float*)d_in[4];
  const float* Wv = (const float*)d_in[5];
  const float* bv = (const float*)d_in[6];
  const float* Wo = (const float*)d_in[7];
  const float* bo = (const float*)d_in[8];
  float* out = (float*)d_out;

  // Workspace carve-up (bytes). Each f16 plane M_*C_ = 8 MB.
  char* ws = (char*)d_ws;
  _Float16* xh   = (_Float16*)(ws);                        // 8 MB
  _Float16* Qh   = (_Float16*)(ws + (((size_t)8)  << 20)); // 8 MB
  _Float16* Kh   = (_Float16*)(ws + (((size_t)16) << 20)); // 8 MB
  _Float16* Vt   = (_Float16*)(ws + (((size_t)24) << 20)); // 8 MB  [b,h,d,t]
  _Float16* Yh   = (_Float16*)(ws + (((size_t)32) << 20)); // 8 MB
  _Float16* Wt3  = (_Float16*)(ws + (((size_t)40) << 20)); // 6 MB  [3072][1024]
  _Float16* Wot  = (_Float16*)(ws + (((size_t)46) << 20)); // 2 MB  [1024][1024]
  float*    b3   = (float*)   (ws + (((size_t)48) << 20)); // 12 KB

  prep_kernel<<<8204, 256, 0, stream>>>(x, Wq, Wk, Wv, Wo, bq, bk, bv,
                                        xh, Wt3, Wot, b3);

  // Fused QKV projection: [4096,1024] @ [1024,3072] -> Q,K (f16) + V^T (f16).
  gemm_f16_kernel<128, 128, 0><<<dim3(24, 32), 256, 0, stream>>>(
      xh, Wt3, b3, Qh, Kh, Vt, nullptr);

  attn_f16_kernel<<<dim3(T_ / 128, H_, B_), 512, 0, stream>>>(Qh, Kh, Vt, Yh);

  // Output projection: Yh @ Wot^T + bo -> fp32 out.
  gemm_f16_kernel<64, 128, 1><<<dim3(8, 64), 256, 0, stream>>>(
      Yh, Wot, bo, nullptr, nullptr, nullptr, out);
}

// Round 6
// 199.633 us; speedup vs baseline: 1.5448x; 1.0659x over previous
//
#include <hip/hip_runtime.h>
#include <math.h>

#define B_ 2
#define T_ 2048
#define C_ 1024
#define H_ 16
#define HD_ 64
#define M_ (B_*T_)

typedef _Float16 half2v __attribute__((ext_vector_type(2)));
typedef _Float16 half4v __attribute__((ext_vector_type(4)));
typedef _Float16 half8v __attribute__((ext_vector_type(8)));
typedef float f32x4 __attribute__((ext_vector_type(4)));

#define GLD_LDS(gp, lp) \
  __builtin_amdgcn_global_load_lds( \
      (const __attribute__((address_space(1))) void*)(gp), \
      (__attribute__((address_space(3))) void*)(lp), 16, 0, 0)

// ---------------------------------------------------------------------------
// Fused prep: fp32->f16 cast of x (blocks 0..4095), 4 weight transposes
// (blocks 4096..8191), bias concat (blocks 8192..8203). One launch.
// ---------------------------------------------------------------------------
__global__ __launch_bounds__(256) void prep_kernel(
    const float* __restrict__ x,
    const float* __restrict__ Wq, const float* __restrict__ Wk,
    const float* __restrict__ Wv, const float* __restrict__ Wo,
    const float* __restrict__ bq, const float* __restrict__ bk,
    const float* __restrict__ bv,
    _Float16* __restrict__ xh, _Float16* __restrict__ Wt3,
    _Float16* __restrict__ Wot, float* __restrict__ b3)
{
  __shared__ float tile[32][33];
  const int blk = blockIdx.x, thr = threadIdx.x;
  if (blk < 4096) {
    int i = blk * 256 + thr;
    float4 v = ((const float4*)x)[i];
    half4v h; h[0] = (_Float16)v.x; h[1] = (_Float16)v.y;
    h[2] = (_Float16)v.z; h[3] = (_Float16)v.w;
    ((half4v*)xh)[i] = h;
  } else if (blk < 8192) {
    int zz = (blk - 4096) >> 10;      // which W
    int bxy = (blk - 4096) & 1023;
    const float* W; _Float16* Wt;
    switch (zz) {
      case 0:  W = Wq; Wt = Wt3; break;
      case 1:  W = Wk; Wt = Wt3 + (size_t)1024 * 1024; break;
      case 2:  W = Wv; Wt = Wt3 + (size_t)2048 * 1024; break;
      default: W = Wo; Wt = Wot; break;
    }
    const int n0 = (bxy & 31) * 32, k0 = (bxy >> 5) * 32;
    const int tx = thr & 31, ty = thr >> 5;  // 32 x 8
#pragma unroll
    for (int r = 0; r < 4; r++) {
      int k = ty + r * 8;
      tile[k][tx] = W[(size_t)(k0 + k) * C_ + n0 + tx];
    }
    __syncthreads();
#pragma unroll
    for (int r = 0; r < 4; r++) {
      int n = ty + r * 8;
      Wt[(size_t)(n0 + n) * C_ + k0 + tx] = (_Float16)tile[tx][n];
    }
  } else {
    int i = (blk - 8192) * 256 + thr;  // 0..3071
    const float* s = (i < 1024) ? bq : ((i < 2048) ? bk : bv);
    b3[i] = s[i & 1023];
  }
}

// ---------------------------------------------------------------------------
// f16 MFMA GEMM: Out[M,N] = A[M,1024] @ Wt[N,1024]^T + bias.
// BK=32, 256 threads = 4 waves (2x2); wave tile (BM/2)x(BN/2).
// Staging via global_load_lds width=16 (m97 pattern).
// EPI 0: fused QKV epilogue. Q (scaled 0.125*log2e) and K: plain 2-B stores.
// V: packed 8-B stores to V^T.  EPI 1: fp32 out + bias (of).
// ---------------------------------------------------------------------------
template <int BM, int BN, int EPI>
__global__ __launch_bounds__(256) void gemm_f16_kernel(
    const _Float16* __restrict__ A, const _Float16* __restrict__ Bw,
    const float* __restrict__ bias,
    _Float16* __restrict__ o0, _Float16* __restrict__ o1,
    _Float16* __restrict__ o2, float* __restrict__ of)
{
  constexpr int FM = BM / 32, FN = BN / 32;
  __shared__ __align__(16) _Float16 As[BM * 32];
  __shared__ __align__(16) _Float16 Bs[BN * 32];
  const int t = threadIdx.x;
  const int w = t >> 6, lane = t & 63, l15 = lane & 15, quad = lane >> 4;
  const int wm = (w & 1) * (BM / 2), wn = (w >> 1) * (BN / 2);
  const int bm = blockIdx.y * BM, bn = blockIdx.x * BN;
  const int lrow = lane >> 2, lcol = (lane & 3) * 8;  // staging: 16 rows/call

  f32x4 acc[FM][FN];
#pragma unroll
  for (int i = 0; i < FM; i++)
#pragma unroll
    for (int j = 0; j < FN; j++) acc[i][j] = (f32x4){0.f, 0.f, 0.f, 0.f};

  for (int k0 = 0; k0 < 1024; k0 += 32) {
#pragma unroll
    for (int i = 0; i < BM / 64; i++) {
      int ca = w + 4 * i;
      int row = ca * 16 + lrow;
      GLD_LDS(A + (size_t)(bm + row) * 1024 + k0 + lcol, As + ca * 512);
    }
#pragma unroll
    for (int i = 0; i < BN / 64; i++) {
      int cb = w + 4 * i;
      int row = cb * 16 + lrow;
      GLD_LDS(Bw + (size_t)(bn + row) * 1024 + k0 + lcol, Bs + cb * 512);
    }
    __syncthreads();

    half8v af[FM], bf[FN];
#pragma unroll
    for (int mt = 0; mt < FM; mt++)
      af[mt] = *(const half8v*)(As + (wm + mt * 16 + l15) * 32 + quad * 8);
#pragma unroll
    for (int nt = 0; nt < FN; nt++)
      bf[nt] = *(const half8v*)(Bs + (wn + nt * 16 + l15) * 32 + quad * 8);
#pragma unroll
    for (int mt = 0; mt < FM; mt++)
#pragma unroll
      for (int nt = 0; nt < FN; nt++)
        acc[mt][nt] = __builtin_amdgcn_mfma_f32_16x16x32_f16(
            af[mt], bf[nt], acc[mt][nt], 0, 0, 0);
    __syncthreads();
  }

  // Epilogue. C/D layout: col = l15 (n), row = quad*4 + r (m).
#pragma unroll
  for (int mt = 0; mt < FM; mt++)
#pragma unroll
    for (int nt = 0; nt < FN; nt++) {
      int n = bn + wn + nt * 16 + l15;
      float bv = bias[n];
      if (EPI == 0 && bn >= 2048) {
        // V region: pack r=0..3 (consecutive t) -> one 8-B store to V^T.
        int dg = n - 2048;
        int hh = dg >> 6, hd = dg & 63;
        int m0 = bm + wm + mt * 16 + quad * 4;
        int bb = m0 >> 11, tt = m0 & 2047;
        half2v p01 = __builtin_bit_cast(half2v,
            __builtin_amdgcn_cvt_pkrtz(acc[mt][nt][0] + bv, acc[mt][nt][1] + bv));
        half2v p23 = __builtin_bit_cast(half2v,
            __builtin_amdgcn_cvt_pkrtz(acc[mt][nt][2] + bv, acc[mt][nt][3] + bv));
        half4v pk = __builtin_shufflevector(p01, p23, 0, 1, 2, 3);
        *(half4v*)(o2 + (((size_t)(bb * H_ + hh) * 64 + hd) * 2048 + tt)) = pk;
      } else {
#pragma unroll
        for (int r = 0; r < 4; r++) {
          int m = bm + wm + mt * 16 + quad * 4 + r;
          float v = acc[mt][nt][r] + bv;
          if (EPI == 0) {
            if (bn < 1024) {
              // Q pre-scaled by 0.125 * log2(e) for base-2 softmax.
              o0[(size_t)m * 1024 + n] = (_Float16)(v * 0.180336884f);
            } else {
              o1[(size_t)m * 1024 + (n - 1024)] = (_Float16)v;    // K
            }
          } else {
            of[(size_t)m * 1024 + n] = v;
          }
        }
      }
    }
}

// ---------------------------------------------------------------------------
// MFMA flash attention (no mask, per reference). Grid (T/128, H, B), 512 thr.
// V15 = round-1 V11 frame EXACTLY, with:
//  (a') PV upgraded 16x16x16 -> 16x16x32 WITHOUT K permutation (round 5's
//       permuted S^T read caused 9x bank conflicts = 20% of cycles).
//       Unpermuted pf[2p] covers keys 32p+4q+(0..3), pf[2p+1] covers
//       32p+16+4q+(0..3); concat IS a valid x32 B-operand when the V^T
//       A-operand is read as TWO half4v at d*264 + p*64 + q*8 and +32 --
//       byte-identical addresses to round-1's PV reads (proven low-conflict),
//       but 16 MFMAs instead of 32.
//  (b) bijective XCD swizzle (round-5-proven: FETCH 69.7 -> 12.3 MB).
//  (c) s_setprio(1) around MFMA clusters (T5).
// LDS: Ks[128][68] + Vs[64][132] = 34.3 KB (2 blocks/CU proven).
// Wave w (0..7) owns q-cols qt*128 + w*16 + l15. Base-2 softmax.
// ---------------------------------------------------------------------------
__global__ __launch_bounds__(512) void attn_f16_kernel(
    const _Float16* __restrict__ Qh, const _Float16* __restrict__ Kh,
    const _Float16* __restrict__ Vt, _Float16* __restrict__ Yh)
{
  __shared__ __align__(16) _Float16 Ks[128 * 68];   // [key][d], 136-B rows
  __shared__ __align__(16) _Float16 Vs[64 * 132];   // [d][t], 264-B rows
  const int t = threadIdx.x;
  const int w = t >> 6, lane = t & 63, l15 = lane & 15, quad = lane >> 4;
  // XCD-aware bijective remap of the 512 linear block ids (x fastest):
  // swz = (lin%8)*64 + lin/8 -> 64-consecutive-work chunks per XCD,
  // each chunk = 4 complete (b,h) groups (their K/V stay in one L2).
  const int lin = blockIdx.x + 16 * blockIdx.y + 256 * blockIdx.z;
  const int swz = (lin & 7) * 64 + (lin >> 3);
  const int qt = swz & 15, h = (swz >> 4) & 15, b = swz >> 8;
  const int qg = qt * 128 + w * 16 + l15;
  const size_t qoff = ((size_t)(b * T_ + qg)) * C_ + h * HD_;

  half8v qf[2];
  qf[0] = *(const half8v*)(Qh + qoff + quad * 8);
  qf[1] = *(const half8v*)(Qh + qoff + 32 + quad * 8);

  f32x4 o[4];
#pragma unroll
  for (int i = 0; i < 4; i++) o[i] = (f32x4){0.f, 0.f, 0.f, 0.f};
  float m_run = -INFINITY, l_run = 0.f;

  const size_t kbase = ((size_t)b * T_) * C_ + h * HD_;
  const size_t vbase = ((size_t)(b * H_ + h)) * HD_ * 2048;

  for (int kt0 = 0; kt0 < T_; kt0 += 128) {
    // Stage K: 128 keys x 64 d = 1024 16-B chunks (2 per thread).
#pragma unroll
    for (int i = 0; i < 2; i++) {
      int slot = t + i * 512;          // 0..1023
      int row = slot >> 3, cp = slot & 7;
      *(uint4*)((char*)Ks + row * 136 + cp * 16) =
          *(const uint4*)(Kh + kbase + (size_t)(kt0 + row) * C_ + cp * 8);
    }
    // Stage V^T: 64 d x 128 t = 1024 16-B chunks (2 per thread).
#pragma unroll
    for (int i = 0; i < 2; i++) {
      int slot = t + i * 512;          // 0..1023
      int row = slot >> 4, cp = slot & 15;
      *(uint4*)((char*)Vs + row * 264 + cp * 16) =
          *(const uint4*)(Vt + vbase + (size_t)row * 2048 + kt0 + cp * 8);
    }
    __syncthreads();

    // S^T tiles: 8 key-tiles x 2 d-steps of 16x16x32 (round-1 unpermuted).
    f32x4 s[8];
    __builtin_amdgcn_s_setprio(1);
#pragma unroll
    for (int kt = 0; kt < 8; kt++) {
      s[kt] = (f32x4){0.f, 0.f, 0.f, 0.f};
      int key = kt * 16 + l15;
#pragma unroll
      for (int ks = 0; ks < 2; ks++) {
        half8v kf = *(const half8v*)((char*)Ks + key * 136 + (ks * 4 + quad) * 16);
        s[kt] = __builtin_amdgcn_mfma_f32_16x16x32_f16(kf, qf[ks], s[kt], 0, 0, 0);
      }
    }
    __builtin_amdgcn_s_setprio(0);

    // Online softmax (base-2) over the 128 keys, per q column = l15.
    float tmax = -INFINITY;
#pragma unroll
    for (int kt = 0; kt < 8; kt++)
#pragma unroll
      for (int r = 0; r < 4; r++) tmax = fmaxf(tmax, s[kt][r]);
    tmax = fmaxf(tmax, __shfl_xor(tmax, 16));
    tmax = fmaxf(tmax, __shfl_xor(tmax, 32));
    float mnew = fmaxf(m_run, tmax);
    float alpha = __builtin_amdgcn_exp2f(m_run - mnew);

    float psum = 0.f;
    half4v pf[8];
#pragma unroll
    for (int kt = 0; kt < 8; kt++) {
      float p0 = __builtin_amdgcn_exp2f(s[kt][0] - mnew);
      float p1 = __builtin_amdgcn_exp2f(s[kt][1] - mnew);
      float p2 = __builtin_amdgcn_exp2f(s[kt][2] - mnew);
      float p3 = __builtin_amdgcn_exp2f(s[kt][3] - mnew);
      psum += (p0 + p1) + (p2 + p3);
      half2v pk01 = __builtin_bit_cast(half2v, __builtin_amdgcn_cvt_pkrtz(p0, p1));
      half2v pk23 = __builtin_bit_cast(half2v, __builtin_amdgcn_cvt_pkrtz(p2, p3));
      pf[kt] = __builtin_shufflevector(pk01, pk23, 0, 1, 2, 3);
    }
    psum += __shfl_xor(psum, 16);
    psum += __shfl_xor(psum, 32);
    l_run = l_run * alpha + psum;
    m_run = mnew;
#pragma unroll
    for (int dt = 0; dt < 4; dt++) o[dt] *= alpha;

    // PV: o^T[d][q] += V^T x P, 4 d-tiles x 4 key-groups of 16x16x32.
    // pf[2p] holds P[32p+4q+(0..3)][q], pf[2p+1] holds P[32p+16+4q+(0..3)][q]
    // -> concat is the x32 B-operand (k=8q+j). Matching V^T A-operand:
    // lane (d=l15-row, quad=q) needs V[d][32p+4q+j] and V[d][32p+16+4q+j]
    // = two half4v at d*264 + p*64 + q*8 (+32) -- same addresses round 1 read.
    __builtin_amdgcn_s_setprio(1);
#pragma unroll
    for (int dt = 0; dt < 4; dt++) {
      int d = dt * 16 + l15;
#pragma unroll
      for (int p = 0; p < 4; p++) {
        half4v v0 = *(const half4v*)((char*)Vs + d * 264 + p * 64 + quad * 8);
        half4v v1 = *(const half4v*)((char*)Vs + d * 264 + p * 64 + 32 + quad * 8);
        half8v vf = __builtin_shufflevector(v0, v1, 0, 1, 2, 3, 4, 5, 6, 7);
        half8v pf8 = __builtin_shufflevector(pf[2 * p], pf[2 * p + 1],
                                             0, 1, 2, 3, 4, 5, 6, 7);
        o[dt] = __builtin_amdgcn_mfma_f32_16x16x32_f16(vf, pf8, o[dt], 0, 0, 0);
      }
    }
    __builtin_amdgcn_s_setprio(0);
    __syncthreads();
  }

  float inv = 1.0f / l_run;
#pragma unroll
  for (int dt = 0; dt < 4; dt++) {
    half4v yv;
#pragma unroll
    for (int r = 0; r < 4; r++) yv[r] = (_Float16)(o[dt][r] * inv);
    *(half4v*)(Yh + qoff + dt * 16 + quad * 4) = yv;  // row q, cols h*64+d..
  }
}

// ---------------------------------------------------------------------------
extern "C" void kernel_launch(void* const* d_in, const int* in_sizes, int n_in,
                              void* d_out, int out_size, void* d_ws, size_t ws_size,
                              hipStream_t stream) {
  const float* x  = (const float*)d_in[0];
  const float* Wq = (const float*)d_in[1];
  const float* bq = (const float*)d_in[2];
  const float* Wk = (const float*)d_in[3];
  const float* bk = (const float*)d_in[4];
  const float* Wv = (const float*)d_in[5];
  const float* bv = (const float*)d_in[6];
  const float* Wo = (const float*)d_in[7];
  const float* bo = (const float*)d_in[8];
  float* out = (float*)d_out;

  // Workspace carve-up (bytes). Each f16 plane M_*C_ = 8 MB.
  char* ws = (char*)d_ws;
  _Float16* xh   = (_Float16*)(ws);                        // 8 MB
  _Float16* Qh   = (_Float16*)(ws + (((size_t)8)  << 20)); // 8 MB
  _Float16* Kh   = (_Float16*)(ws + (((size_t)16) << 20)); // 8 MB
  _Float16* Vt   = (_Float16*)(ws + (((size_t)24) << 20)); // 8 MB  [b,h,d,t]
  _Float16* Yh   = (_Float16*)(ws + (((size_t)32) << 20)); // 8 MB
  _Float16* Wt3  = (_Float16*)(ws + (((size_t)40) << 20)); // 6 MB  [3072][1024]
  _Float16* Wot  = (_Float16*)(ws + (((size_t)46) << 20)); // 2 MB  [1024][1024]
  float*    b3   = (float*)   (ws + (((size_t)48) << 20)); // 12 KB

  prep_kernel<<<8204, 256, 0, stream>>>(x, Wq, Wk, Wv, Wo, bq, bk, bv,
                                        xh, Wt3, Wot, b3);

  // Fused QKV projection: [4096,1024] @ [1024,3072] -> Q,K (f16) + V^T (f16).
  gemm_f16_kernel<128, 128, 0><<<dim3(24, 32), 256, 0, stream>>>(
      xh, Wt3, b3, Qh, Kh, Vt, nullptr);

  attn_f16_kernel<<<dim3(T_ / 128, H_, B_), 512, 0, stream>>>(Qh, Kh, Vt, Yh);

  // Output projection: Yh @ Wot^T + bo -> fp32 out.
  gemm_f16_kernel<64, 128, 1><<<dim3(8, 64), 256, 0, stream>>>(
      Yh, Wot, bo, nullptr, nullptr, nullptr, out);
}